// Round 15
// baseline (362.420 us; speedup 1.0000x reference)
//
#include <hip/hip_runtime.h>
#include <stdint.h>

#define NSUP 65536
#define NQRY 65536
#define FEAT 1024
#define EMB  512
#define WAYS 256

typedef unsigned short u16;
typedef unsigned int   u32;
typedef __attribute__((ext_vector_type(8))) __bf16 bf16x8;
typedef __attribute__((ext_vector_type(4))) float  f32x4;

// RNE float -> bf16 bits
static __device__ __forceinline__ u16 f2bf(float f) {
    u32 u = __builtin_bit_cast(u32, f);
    u32 r = u + 0x7fffu + ((u >> 16) & 1u);
    return (u16)(r >> 16);
}

// async global -> LDS, 16B per lane (dest must be wave-uniform base + lane*16)
static __device__ __forceinline__ void gl_lds16(const void* g, void* l) {
    __builtin_amdgcn_global_load_lds((const __attribute__((address_space(1))) u32*)g,
                                     (__attribute__((address_space(3))) u32*)l,
                                     16, 0, 0);
}

// swizzled u16-index in a [rows][32 u16] tile: source slot s of row r stored at
// slot s ^ ((r>>1)&3) -> conflict-free b128 reads (verified: SQ_LDS_BANK_CONFLICT=0).
static __device__ __forceinline__ int swz16(int r, int s) {
    return r * 32 + ((s ^ ((r >> 1) & 3)) * 8);
}

// ---------------- K0: W [FEAT][EMB] f32 -> Wt [EMB][FEAT] bf16 (+ zero icounts) ----------------
__global__ __launch_bounds__(256) void k0_transpose(const float* __restrict__ W,
                                                    u16* __restrict__ Wt,
                                                    int* __restrict__ icounts) {
    const int t = threadIdx.x;
    if (blockIdx.x == 0) icounts[t] = 0;   // replaces hipMemsetAsync node (~150us each)
    __shared__ float tile[64][65];
    const int bx = blockIdx.x;
    const int k0 = (bx & 15) * 64;
    const int e0 = (bx >> 4) * 64;
#pragma unroll
    for (int i = 0; i < 16; ++i) {
        int idx = t + i * 256;
        int kk = idx >> 6, ee = idx & 63;
        tile[kk][ee] = W[(size_t)(k0 + kk) * EMB + e0 + ee];
    }
    __syncthreads();
#pragma unroll
    for (int i = 0; i < 16; ++i) {
        int idx = t + i * 256;
        int ee = idx >> 6, kk = idx & 63;
        Wt[(size_t)(e0 + ee) * FEAT + k0 + kk] = f2bf(tile[kk][ee]);
    }
}

// ---------------- K1a: argmax of one-hot rows -> labels, int histogram ----------------
__global__ __launch_bounds__(256) void k1a_labels(const int* __restrict__ sl,
                                                  int* __restrict__ labels,
                                                  int* __restrict__ icounts) {
    const int row = blockIdx.x * 4 + (threadIdx.x >> 6);
    const int lane = threadIdx.x & 63;
    const int4* p = (const int4*)(sl + (size_t)row * WAYS);
    int4 v = p[lane];
    int my = -1;
    if (v.x) my = lane * 4 + 0;
    if (v.y) my = lane * 4 + 1;
    if (v.z) my = lane * 4 + 2;
    if (v.w) my = lane * 4 + 3;
#pragma unroll
    for (int m = 32; m; m >>= 1) my = max(my, __shfl_xor(my, m));
    if (lane == 0) {
        labels[row] = my;
        atomicAdd(&icounts[my], 1);
    }
}

// ---------------- K1p: exclusive prefix sum over 256 class counts ----------------
__global__ __launch_bounds__(256) void k1p_prefix(const int* __restrict__ icounts,
                                                  int* __restrict__ offs,
                                                  int* __restrict__ cursor,
                                                  float* __restrict__ countsF) {
    __shared__ int s[256];
    const int t = threadIdx.x;
    const int v = icounts[t];
    s[t] = v;
    __syncthreads();
    for (int d = 1; d < 256; d <<= 1) {
        int x = (t >= d) ? s[t - d] : 0;
        __syncthreads();
        s[t] += x;
        __syncthreads();
    }
    const int exc = s[t] - v;
    offs[t] = exc;
    cursor[t] = exc;
    countsF[t] = (float)v;
}

// ---------------- K1s: scatter row indices by class -> perm ----------------
__global__ __launch_bounds__(256) void k1s_scatter(const int* __restrict__ labels,
                                                   int* __restrict__ cursor,
                                                   int* __restrict__ perm) {
    const int r = blockIdx.x * 256 + threadIdx.x;
    const int lb = labels[r];
    const int pos = atomicAdd(&cursor[lb], 1);
    perm[pos] = r;
}

// ---------------- K2: protos: (sums/count) @ W  -> zp_bf16 [WAYS][EMB], p2 ----------------
// NOTE: bias b deliberately omitted everywhere — it cancels in euclidean distance.
__global__ __launch_bounds__(512) void k2_proto(const float* __restrict__ sums,
                                                const float* __restrict__ counts,
                                                const float* __restrict__ W,
                                                u16* __restrict__ zpb,
                                                float* __restrict__ p2) {
    __shared__ float proto[FEAT];
    __shared__ float red[8];
    const int c = blockIdx.x, t = threadIdx.x;
    const float inv = 1.0f / counts[c];
    proto[t]       = sums[(size_t)c * FEAT + t] * inv;
    proto[t + 512] = sums[(size_t)c * FEAT + t + 512] * inv;
    __syncthreads();
    float a0 = 0.f, a1 = 0.f, a2 = 0.f, a3 = 0.f;
#pragma unroll 8
    for (int k = 0; k < FEAT; k += 4) {
        a0 += proto[k + 0] * W[(size_t)(k + 0) * EMB + t];
        a1 += proto[k + 1] * W[(size_t)(k + 1) * EMB + t];
        a2 += proto[k + 2] * W[(size_t)(k + 2) * EMB + t];
        a3 += proto[k + 3] * W[(size_t)(k + 3) * EMB + t];
    }
    float z = (a0 + a1) + (a2 + a3);
    zpb[(size_t)c * EMB + t] = f2bf(z);
    float sq = z * z;
#pragma unroll
    for (int m = 1; m < 64; m <<= 1) sq += __shfl_xor(sq, m);
    if ((t & 63) == 0) red[t >> 6] = sq;
    __syncthreads();
    if (t == 0) {
        float s = 0.f;
#pragma unroll
        for (int i = 0; i < 8; ++i) s += red[i];
        p2[c] = s;
    }
}

// ---------------- K13: FUSED classsum + zq GEMM — 512-thread blocks, 2 blocks/CU ----------
// R14 post-mortem: the 1024-thread GEMM is ONE barrier group per CU (reg-capped), so
// every per-iter serial cost is fully exposed; counted-vmcnt didn't help (205 vs 208).
// Fix: 512 threads / 8 waves, tile 64M x 512N (Q still read once), wave tile 64x64,
// acc[4][4] (~124 regs), LDS 72 KiB -> TWO independent blocks per CU whose barrier
// stalls overlap (m114 wave-level TLP). Plain 2-phase dbuf, proven swz16 (0 conflicts).
// bx%5==4 -> classsum block (c = bx/5, 2 feature cols/thread); else GEMM kb 0..1023.
__global__ __launch_bounds__(512, 4) void k13_fused(const float* __restrict__ Q,
                                                    const u16* __restrict__ Wt,
                                                    u16* __restrict__ zq,
                                                    float* __restrict__ q2,
                                                    const float* __restrict__ img,
                                                    const int* __restrict__ perm,
                                                    const int* __restrict__ offs,
                                                    const int* __restrict__ icounts,
                                                    float* __restrict__ sums) {
    const int bx = blockIdx.x;
    const int t = threadIdx.x;

    if (bx % 5 == 4) {
        // ----- classsum: block owns class c; thread t sums feature cols t and t+512 -----
        const int c = bx / 5;
        const int base = offs[c];
        const int n    = icounts[c];
        float a0 = 0.f, a1 = 0.f;
        int i = 0;
        for (; i + 8 <= n; i += 8) {
            int rr[8];
#pragma unroll
            for (int u = 0; u < 8; ++u) rr[u] = perm[base + i + u];
            float v0[8], v1[8];
#pragma unroll
            for (int u = 0; u < 8; ++u) {
                const float* rp = img + (size_t)rr[u] * FEAT;
                v0[u] = rp[t];
                v1[u] = rp[t + 512];
            }
#pragma unroll
            for (int u = 0; u < 8; ++u) { a0 += v0[u]; a1 += v1[u]; }
        }
        for (; i < n; ++i) {
            const float* rp = img + (size_t)perm[base + i] * FEAT;
            a0 += rp[t];
            a1 += rp[t + 512];
        }
        sums[(size_t)c * FEAT + t]       = a0;
        sums[(size_t)c * FEAT + t + 512] = a1;
        return;
    }

    // ----- GEMM block: 64 rows x full 512 cols -----
    const int kb = (bx / 5) * 4 + (bx % 5);   // 0..1023
    __shared__ u16 Asl[2][64 * 32];    // 4 KiB each
    __shared__ u16 Bsl[2][512 * 32];   // 32 KiB each — total 72 KiB -> 2 blocks/CU
    const int lane = t & 63, wave = t >> 6;   // 8 waves, 1m x 8n
    const int wn = wave;
    const int L = lane & 15, g = lane >> 4;
    const size_t row0 = (size_t)kb * 64;

    // A staging: thread t -> row t>>3 (0..63), 4 f32 at offset (t&7)*4
    const float* aptr = Q + (row0 + (t >> 3)) * FEAT + (t & 7) * 4;
    const int aw = swz16(t >> 3, (t & 7) >> 1) + (t & 1) * 4;
    float4 af;

    auto loadA = [&](int ks) { af = *(const float4*)(aptr + ks * 32); };
    auto writeA = [&](int buf) {
        uint2 w;
        w.x = (u32)f2bf(af.x) | ((u32)f2bf(af.y) << 16);
        w.y = (u32)f2bf(af.z) | ((u32)f2bf(af.w) << 16);
        *(uint2*)&Asl[buf][aw] = w;
    };
    // B staging: 2048 granules of 16B over 512 threads; source pre-swizzled
    auto stageB = [&](int buf, int ks) {
#pragma unroll
        for (int p = 0; p < 4; ++p) {
            int gi = t + p * 512;
            int r = gi >> 2, cc = gi & 3;
            int s = cc ^ ((r >> 1) & 3);
            gl_lds16(Wt + (size_t)r * FEAT + ks * 32 + s * 8, &Bsl[buf][gi * 8]);
        }
    };

    f32x4 acc[4][4];
#pragma unroll
    for (int mt = 0; mt < 4; ++mt)
#pragma unroll
        for (int nt = 0; nt < 4; ++nt) acc[mt][nt] = f32x4{0.f, 0.f, 0.f, 0.f};

    stageB(0, 0);
    loadA(0);
    writeA(0);
    __syncthreads();

    const int ard = swz16(L, g);              // + mt*512  (row = mt*16 + L)
    const int brd = swz16(wn * 64 + L, g);    // + nt*512

    int cur = 0;
    for (int ks = 0; ks < 32; ++ks) {
        const int nxt = cur ^ 1;
        if (ks < 31) { stageB(nxt, ks + 1); loadA(ks + 1); }
        bf16x8 a[4], b[4];
#pragma unroll
        for (int mt = 0; mt < 4; ++mt) a[mt] = *(const bf16x8*)&Asl[cur][ard + mt * 512];
#pragma unroll
        for (int nt = 0; nt < 4; ++nt) b[nt] = *(const bf16x8*)&Bsl[cur][brd + nt * 512];
#pragma unroll
        for (int mt = 0; mt < 4; ++mt)
#pragma unroll
            for (int nt = 0; nt < 4; ++nt)
                acc[mt][nt] = __builtin_amdgcn_mfma_f32_16x16x32_bf16(a[mt], b[nt], acc[mt][nt], 0, 0, 0);
        if (ks < 31) writeA(nxt);
        __syncthreads();
        cur = nxt;
    }

    // epilogue: zq bf16 out; q2 partials -> dead LDS (Asl area) -> fixed-order final sum
    float* q2part = (float*)&Asl[0][0];   // [8 wn][64 rows] = 2 KiB (Asl dead)
    const int c = L;
#pragma unroll
    for (int mt = 0; mt < 4; ++mt) {
#pragma unroll
        for (int j = 0; j < 4; ++j) {
            const int rloc = mt * 16 + g * 4 + j;
            const size_t r = row0 + rloc;
            float ss = 0.f;
#pragma unroll
            for (int nt = 0; nt < 4; ++nt) {
                float v = acc[mt][nt][j];
                ss += v * v;
                zq[r * EMB + wn * 64 + nt * 16 + c] = f2bf(v);
            }
#pragma unroll
            for (int m = 1; m < 16; m <<= 1) ss += __shfl_xor(ss, m);
            if (c == 0) q2part[wn * 64 + rloc] = ss;
        }
    }
    __syncthreads();
    if (t < 64) {
        float s0 = 0.f;
#pragma unroll
        for (int p = 0; p < 8; ++p) s0 += q2part[p * 64 + t];   // fixed order
        q2[row0 + t] = s0;
    }
}

// ---------------- K4: cross GEMM + distances + row softmax ----------------
// A (zq rows) held in registers (loaded ONCE); zp staged via LDS in 8 chunks of
// 32 ways x full K (32 KB, swz16 -> conflict-free) so each block fetches zp from
// L2 exactly once (R9 lesson: per-wave global B-reads are L1-miss-latency-bound).
// 256 threads = 4 waves, 64 rows/block; softmax wave-local (16-lane shfl).
__global__ __launch_bounds__(256, 2) void k4_scores(const u16* __restrict__ zq,
                                                    const u16* __restrict__ zp,
                                                    const float* __restrict__ q2,
                                                    const float* __restrict__ p2,
                                                    float* __restrict__ out) {
    __shared__ u16 zps[16][32 * 32];   // [kchunk][32 ways][32 u16] = 32 KiB
    const int t = threadIdx.x;
    const int lane = t & 63, wave = t >> 6;
    const int L = lane & 15, g = lane >> 4;
    const size_t row0 = (size_t)blockIdx.x * 64 + wave * 16;

    // A fragments in registers: lane holds row (row0+L), k-slice g*8 of each ks
    bf16x8 a[16];
    const u16* arow = zq + (row0 + L) * EMB + g * 8;
#pragma unroll
    for (int ks = 0; ks < 16; ++ks) a[ks] = *(const bf16x8*)(arow + ks * 32);

    float q2v[4];
#pragma unroll
    for (int j = 0; j < 4; ++j) q2v[j] = q2[row0 + g * 4 + j];
    float p2v[16];
#pragma unroll
    for (int i = 0; i < 16; ++i) p2v[i] = p2[i * 16 + L];

    f32x4 acc[16];
#pragma unroll
    for (int i = 0; i < 16; ++i) acc[i] = f32x4{0.f, 0.f, 0.f, 0.f};

    for (int c = 0; c < 8; ++c) {
        if (c) __syncthreads();            // prior chunk's LDS reads complete
        // stage 32 ways x 512 cols: 2048 granules of 16B over 256 threads
#pragma unroll
        for (int p = 0; p < 8; ++p) {
            int gi = t + p * 256;
            int kc = gi >> 7, way = (gi >> 2) & 31, slot = gi & 3;
            int s = slot ^ ((way >> 1) & 3);   // pre-swizzled source (dest stays linear)
            gl_lds16(zp + (size_t)(c * 32 + way) * EMB + kc * 32 + s * 8,
                     ((u16*)zps) + gi * 8);
        }
        asm volatile("s_waitcnt vmcnt(0)" ::: "memory");
        __syncthreads();                   // chunk landed
#pragma unroll
        for (int ks = 0; ks < 16; ++ks) {
#pragma unroll
            for (int nt = 0; nt < 2; ++nt) {
                bf16x8 b = *(const bf16x8*)&zps[ks][swz16(nt * 16 + L, g)];
                acc[c * 2 + nt] = __builtin_amdgcn_mfma_f32_16x16x32_bf16(a[ks], b, acc[c * 2 + nt], 0, 0, 0);
            }
        }
    }

    // distances + wave-local softmax (C layout: row = g*4+j, col/way = i*16+L)
    float mx[4] = {-1e30f, -1e30f, -1e30f, -1e30f};
#pragma unroll
    for (int i = 0; i < 16; ++i)
#pragma unroll
        for (int j = 0; j < 4; ++j) {
            float d2 = q2v[j] + p2v[i] - 2.f * acc[i][j];
            float s = -sqrtf(fmaxf(d2, 0.f));
            acc[i][j] = s;
            mx[j] = fmaxf(mx[j], s);
        }
#pragma unroll
    for (int j = 0; j < 4; ++j)
#pragma unroll
        for (int m = 1; m < 16; m <<= 1) mx[j] = fmaxf(mx[j], __shfl_xor(mx[j], m));

    float sm[4] = {0.f, 0.f, 0.f, 0.f};
#pragma unroll
    for (int i = 0; i < 16; ++i)
#pragma unroll
        for (int j = 0; j < 4; ++j) {
            float e = __expf(acc[i][j] - mx[j]);
            acc[i][j] = e;
            sm[j] += e;
        }
#pragma unroll
    for (int j = 0; j < 4; ++j) {
#pragma unroll
        for (int m = 1; m < 16; m <<= 1) sm[j] += __shfl_xor(sm[j], m);
        sm[j] = 1.f / sm[j];
    }
#pragma unroll
    for (int i = 0; i < 16; ++i)
#pragma unroll
        for (int j = 0; j < 4; ++j)
            out[(row0 + g * 4 + j) * WAYS + i * 16 + L] = acc[i][j] * sm[j];
}

// ---------------- launch ----------------
extern "C" void kernel_launch(void* const* d_in, const int* in_sizes, int n_in,
                              void* d_out, int out_size, void* d_ws, size_t ws_size,
                              hipStream_t stream) {
    (void)in_sizes; (void)n_in; (void)out_size; (void)ws_size;
    const float* simg = (const float*)d_in[0];
    const int*   slab = (const int*)d_in[1];
    const float* qimg = (const float*)d_in[2];
    const float* W    = (const float*)d_in[3];
    // d_in[4] = b : omitted on purpose (cancels in euclidean distance)
    float* out = (float*)d_out;
    char* ws = (char*)d_ws;

    int*   labels = (int*)  (ws + 0);          // 256 KiB
    int*   perm   = (int*)  (ws + 262144);     // 256 KiB
    int*   icounts= (int*)  (ws + 524288);     // 1 KiB
    int*   offs   = (int*)  (ws + 525312);     // 1 KiB
    int*   cursor = (int*)  (ws + 526336);     // 1 KiB
    float* countsF= (float*)(ws + 527360);     // 1 KiB
    float* sums   = (float*)(ws + 528384);     // 1 MiB
    float* p2     = (float*)(ws + 1576960);    // 1 KiB
    u16*   zpb    = (u16*)  (ws + 1577984);    // 256 KiB
    u16*   Wt     = (u16*)  (ws + 1840128);    // 1 MiB
    u16*   zq     = (u16*)  (ws + 2888704);    // 64 MiB
    float* q2     = (float*)(ws + 69997568);   // 256 KiB (final, summed in k13)

    // NO hipMemsetAsync: icounts zeroed in k0; zq/q2/sums fully overwritten before reads.

    k0_transpose <<<128,        256, 0, stream>>>(W, Wt, icounts);
    k1a_labels   <<<NSUP / 4,   256, 0, stream>>>(slab, labels, icounts);
    k1p_prefix   <<<1,          256, 0, stream>>>(icounts, offs, cursor, countsF);
    k1s_scatter  <<<NSUP / 256, 256, 0, stream>>>(labels, cursor, perm);
    k13_fused    <<<1280,       512, 0, stream>>>(qimg, Wt, zq, q2,
                                                  simg, perm, offs, icounts, sums);
    k2_proto     <<<WAYS,       512, 0, stream>>>(sums, countsF, W, zpb, p2);
    k4_scores    <<<NQRY / 64,  256, 0, stream>>>(zq, zpb, q2, p2, out);
}

// Round 16
// 320.061 us; speedup vs baseline: 1.1323x; 1.1323x over previous
//
#include <hip/hip_runtime.h>
#include <stdint.h>

#define NSUP 65536
#define NQRY 65536
#define FEAT 1024
#define EMB  512
#define WAYS 256

typedef unsigned short u16;
typedef unsigned int   u32;
typedef __attribute__((ext_vector_type(8))) __bf16 bf16x8;
typedef __attribute__((ext_vector_type(4))) float  f32x4;

// RNE float -> bf16 bits
static __device__ __forceinline__ u16 f2bf(float f) {
    u32 u = __builtin_bit_cast(u32, f);
    u32 r = u + 0x7fffu + ((u >> 16) & 1u);
    return (u16)(r >> 16);
}

// async global -> LDS, 16B per lane (dest must be wave-uniform base + lane*16)
static __device__ __forceinline__ void gl_lds16(const void* g, void* l) {
    __builtin_amdgcn_global_load_lds((const __attribute__((address_space(1))) u32*)g,
                                     (__attribute__((address_space(3))) u32*)l,
                                     16, 0, 0);
}

// swizzled u16-index in a [rows][32 u16] tile (4 slots of 8): slot s of row r at
// s ^ ((r>>1)&3) -> conflict-free b128 reads. Used by k4.
static __device__ __forceinline__ int swz16(int r, int s) {
    return r * 32 + ((s ^ ((r >> 1) & 3)) * 8);
}
// swizzled u16-index in a [rows][64 u16] tile (8 slots of 8): slot s of row r at
// s ^ (r&7). Write: 8 slots x 16B = 128B covers all 32 banks (conflict-free);
// read: 16 lanes x same slot -> 8 distinct bank-quads, 2-way (free, m136).
static __device__ __forceinline__ int swz64(int r, int s) {
    return r * 64 + ((s ^ (r & 7)) * 8);
}

// ---------------- K0: W [FEAT][EMB] f32 -> Wt [EMB][FEAT] bf16 (+ zero icounts) ----------------
__global__ __launch_bounds__(256) void k0_transpose(const float* __restrict__ W,
                                                    u16* __restrict__ Wt,
                                                    int* __restrict__ icounts) {
    const int t = threadIdx.x;
    if (blockIdx.x == 0) icounts[t] = 0;   // replaces hipMemsetAsync node (~150us each)
    __shared__ float tile[64][65];
    const int bx = blockIdx.x;
    const int k0 = (bx & 15) * 64;
    const int e0 = (bx >> 4) * 64;
#pragma unroll
    for (int i = 0; i < 16; ++i) {
        int idx = t + i * 256;
        int kk = idx >> 6, ee = idx & 63;
        tile[kk][ee] = W[(size_t)(k0 + kk) * EMB + e0 + ee];
    }
    __syncthreads();
#pragma unroll
    for (int i = 0; i < 16; ++i) {
        int idx = t + i * 256;
        int ee = idx >> 6, kk = idx & 63;
        Wt[(size_t)(e0 + ee) * FEAT + k0 + kk] = f2bf(tile[kk][ee]);
    }
}

// ---------------- K1a: argmax of one-hot rows -> labels, int histogram ----------------
__global__ __launch_bounds__(256) void k1a_labels(const int* __restrict__ sl,
                                                  int* __restrict__ labels,
                                                  int* __restrict__ icounts) {
    const int row = blockIdx.x * 4 + (threadIdx.x >> 6);
    const int lane = threadIdx.x & 63;
    const int4* p = (const int4*)(sl + (size_t)row * WAYS);
    int4 v = p[lane];
    int my = -1;
    if (v.x) my = lane * 4 + 0;
    if (v.y) my = lane * 4 + 1;
    if (v.z) my = lane * 4 + 2;
    if (v.w) my = lane * 4 + 3;
#pragma unroll
    for (int m = 32; m; m >>= 1) my = max(my, __shfl_xor(my, m));
    if (lane == 0) {
        labels[row] = my;
        atomicAdd(&icounts[my], 1);
    }
}

// ---------------- K1p: exclusive prefix sum over 256 class counts ----------------
__global__ __launch_bounds__(256) void k1p_prefix(const int* __restrict__ icounts,
                                                  int* __restrict__ offs,
                                                  int* __restrict__ cursor,
                                                  float* __restrict__ countsF) {
    __shared__ int s[256];
    const int t = threadIdx.x;
    const int v = icounts[t];
    s[t] = v;
    __syncthreads();
    for (int d = 1; d < 256; d <<= 1) {
        int x = (t >= d) ? s[t - d] : 0;
        __syncthreads();
        s[t] += x;
        __syncthreads();
    }
    const int exc = s[t] - v;
    offs[t] = exc;
    cursor[t] = exc;
    countsF[t] = (float)v;
}

// ---------------- K1s: scatter row indices by class -> perm ----------------
__global__ __launch_bounds__(256) void k1s_scatter(const int* __restrict__ labels,
                                                   int* __restrict__ cursor,
                                                   int* __restrict__ perm) {
    const int r = blockIdx.x * 256 + threadIdx.x;
    const int lb = labels[r];
    const int pos = atomicAdd(&cursor[lb], 1);
    perm[pos] = r;
}

// ---------------- K2: protos: (sums/count) @ W  -> zp_bf16 [WAYS][EMB], p2 ----------------
// NOTE: bias b deliberately omitted everywhere — it cancels in euclidean distance.
__global__ __launch_bounds__(512) void k2_proto(const float* __restrict__ sums,
                                                const float* __restrict__ counts,
                                                const float* __restrict__ W,
                                                u16* __restrict__ zpb,
                                                float* __restrict__ p2) {
    __shared__ float proto[FEAT];
    __shared__ float red[8];
    const int c = blockIdx.x, t = threadIdx.x;
    const float inv = 1.0f / counts[c];
    proto[t]       = sums[(size_t)c * FEAT + t] * inv;
    proto[t + 512] = sums[(size_t)c * FEAT + t + 512] * inv;
    __syncthreads();
    float a0 = 0.f, a1 = 0.f, a2 = 0.f, a3 = 0.f;
#pragma unroll 8
    for (int k = 0; k < FEAT; k += 4) {
        a0 += proto[k + 0] * W[(size_t)(k + 0) * EMB + t];
        a1 += proto[k + 1] * W[(size_t)(k + 1) * EMB + t];
        a2 += proto[k + 2] * W[(size_t)(k + 2) * EMB + t];
        a3 += proto[k + 3] * W[(size_t)(k + 3) * EMB + t];
    }
    float z = (a0 + a1) + (a2 + a3);
    zpb[(size_t)c * EMB + t] = f2bf(z);
    float sq = z * z;
#pragma unroll
    for (int m = 1; m < 64; m <<= 1) sq += __shfl_xor(sq, m);
    if ((t & 63) == 0) red[t >> 6] = sq;
    __syncthreads();
    if (t == 0) {
        float s = 0.f;
#pragma unroll
        for (int i = 0; i < 8; ++i) s += red[i];
        p2[c] = s;
    }
}

// ---------------- K13: FUSED classsum + zq GEMM, BK=64 (16 barriers, not 32) ----------
// bx%3==2 -> classsum block; else GEMM block: full-N 128x512 tile, BK=64, 1024 thr =
// 16 waves (2m x 8n), wave tile 64x64, acc[4][4], plain 2-phase __syncthreads dbuf
// (proven R8/R11/R14-correct). LDS = 2x16K (A) + 2x64K (B) = 160 KB (HW max; we are
// register-capped to 1 block/CU anyway). R14 post-mortem: per-iter fixed cost ~3000cyc
// dominates and schedule tricks don't move it -> halve the iteration count instead.
__global__ __launch_bounds__(1024, 4) void k13_fused(const float* __restrict__ Q,
                                                     const u16* __restrict__ Wt,
                                                     u16* __restrict__ zq,
                                                     float* __restrict__ q2,
                                                     const float* __restrict__ img,
                                                     const int* __restrict__ perm,
                                                     const int* __restrict__ offs,
                                                     const int* __restrict__ icounts,
                                                     float* __restrict__ sums) {
    const int bx = blockIdx.x;
    const int t = threadIdx.x;

    if (bx % 3 == 2) {
        // ----- classsum: block owns class c, all 1024 features (4KB/row coalesced) -----
        const int c = bx / 3;
        const int base = offs[c];
        const int n    = icounts[c];
        float acc = 0.f;
        int i = 0;
        for (; i + 8 <= n; i += 8) {
            int rr[8];
#pragma unroll
            for (int u = 0; u < 8; ++u) rr[u] = perm[base + i + u];
            float v[8];
#pragma unroll
            for (int u = 0; u < 8; ++u) v[u] = img[(size_t)rr[u] * FEAT + t];
#pragma unroll
            for (int u = 0; u < 8; ++u) acc += v[u];
        }
        for (; i < n; ++i) acc += img[(size_t)perm[base + i] * FEAT + t];
        sums[(size_t)c * FEAT + t] = acc;
        return;
    }

    // ----- GEMM block -----
    const int kb = (bx / 3) * 2 + (bx % 3);   // 0..511
    __shared__ u16 Asl[2][128 * 64];   // 16 KiB each
    __shared__ u16 Bsl[2][512 * 64];   // 64 KiB each — total 163840 B (160 KiB max)
    const int lane = t & 63, wave = t >> 6;     // 16 waves
    const int wm = wave >> 3, wn = wave & 7;    // 2m x 8n
    const int L = lane & 15, g = lane >> 4;
    const size_t row0 = (size_t)kb * 128;

    // A staging: thread t owns row t>>3, 8 f32 at col (t&7)*8 of the 64-col slab.
    const float* aptr = Q + (row0 + (t >> 3)) * FEAT + (t & 7) * 8;
    const int aw = swz64(t >> 3, t & 7);   // 16B (8 bf16) per thread, bank-clean
    float af[8];

    auto loadA = [&](int ks) {
        const float4* p = (const float4*)(aptr + ks * 64);
        float4 x = p[0], y = p[1];
        af[0] = x.x; af[1] = x.y; af[2] = x.z; af[3] = x.w;
        af[4] = y.x; af[5] = y.y; af[6] = y.z; af[7] = y.w;
    };
    auto writeA = [&](int buf) {
        uint4 w;
        w.x = (u32)f2bf(af[0]) | ((u32)f2bf(af[1]) << 16);
        w.y = (u32)f2bf(af[2]) | ((u32)f2bf(af[3]) << 16);
        w.z = (u32)f2bf(af[4]) | ((u32)f2bf(af[5]) << 16);
        w.w = (u32)f2bf(af[6]) | ((u32)f2bf(af[7]) << 16);
        *(uint4*)&Asl[buf][aw] = w;
    };
    // B staging: 4096 granules of 16B over 1024 threads (4 each); source pre-swizzled
    auto stageB = [&](int buf, int ks) {
#pragma unroll
        for (int p = 0; p < 4; ++p) {
            int gi = t + p * 1024;
            int r = gi >> 3, s = gi & 7;
            gl_lds16(Wt + (size_t)r * FEAT + ks * 64 + (s ^ (r & 7)) * 8,
                     &Bsl[buf][gi * 8]);
        }
    };

    f32x4 acc[4][4];
#pragma unroll
    for (int mt = 0; mt < 4; ++mt)
#pragma unroll
        for (int nt = 0; nt < 4; ++nt) acc[mt][nt] = f32x4{0.f, 0.f, 0.f, 0.f};

    stageB(0, 0);
    loadA(0);
    writeA(0);
    __syncthreads();

    int cur = 0;
    for (int ks = 0; ks < 16; ++ks) {
        const int nxt = cur ^ 1;
        if (ks < 15) { stageB(nxt, ks + 1); loadA(ks + 1); }
        // compute both 32-k halves of the 64-k slab, accumulating into acc
#pragma unroll
        for (int h = 0; h < 2; ++h) {
            bf16x8 a[4], b[4];
#pragma unroll
            for (int mt = 0; mt < 4; ++mt) {
                const int r = wm * 64 + mt * 16 + L;
                a[mt] = *(const bf16x8*)&Asl[cur][swz64(r, h * 4 + g)];
            }
#pragma unroll
            for (int nt = 0; nt < 4; ++nt) {
                const int r = wn * 64 + nt * 16 + L;
                b[nt] = *(const bf16x8*)&Bsl[cur][swz64(r, h * 4 + g)];
            }
#pragma unroll
            for (int mt = 0; mt < 4; ++mt)
#pragma unroll
                for (int nt = 0; nt < 4; ++nt)
                    acc[mt][nt] = __builtin_amdgcn_mfma_f32_16x16x32_bf16(a[mt], b[nt], acc[mt][nt], 0, 0, 0);
        }
        if (ks < 15) writeA(nxt);
        __syncthreads();
        cur = nxt;
    }

    // epilogue: zq bf16 out; q2 partials -> dead LDS (Asl area) -> fixed-order final sum
    float* q2part = (float*)&Asl[0][0];   // [8 wn][128 rows] = 4 KiB
    const int c = L;
#pragma unroll
    for (int mt = 0; mt < 4; ++mt) {
#pragma unroll
        for (int j = 0; j < 4; ++j) {
            const int rloc = wm * 64 + mt * 16 + g * 4 + j;
            const size_t r = row0 + rloc;
            float ss = 0.f;
#pragma unroll
            for (int nt = 0; nt < 4; ++nt) {
                float v = acc[mt][nt][j];
                ss += v * v;
                zq[r * EMB + wn * 64 + nt * 16 + c] = f2bf(v);
            }
#pragma unroll
            for (int m = 1; m < 16; m <<= 1) ss += __shfl_xor(ss, m);
            if (c == 0) q2part[wn * 128 + rloc] = ss;
        }
    }
    __syncthreads();
    if (t < 128) {
        float s0 = 0.f;
#pragma unroll
        for (int p = 0; p < 8; ++p) s0 += q2part[p * 128 + t];   // fixed order
        q2[row0 + t] = s0;
    }
}

// ---------------- K4: cross GEMM + distances + row softmax ----------------
// A (zq rows) held in registers (loaded ONCE); zp staged via LDS in 8 chunks of
// 32 ways x full K (32 KB, swz16 -> conflict-free) so each block fetches zp from
// L2 exactly once (R9 lesson: per-wave global B-reads are L1-miss-latency-bound).
// 256 threads = 4 waves, 64 rows/block; softmax wave-local (16-lane shfl).
__global__ __launch_bounds__(256, 2) void k4_scores(const u16* __restrict__ zq,
                                                    const u16* __restrict__ zp,
                                                    const float* __restrict__ q2,
                                                    const float* __restrict__ p2,
                                                    float* __restrict__ out) {
    __shared__ u16 zps[16][32 * 32];   // [kchunk][32 ways][32 u16] = 32 KiB
    const int t = threadIdx.x;
    const int lane = t & 63, wave = t >> 6;
    const int L = lane & 15, g = lane >> 4;
    const size_t row0 = (size_t)blockIdx.x * 64 + wave * 16;

    // A fragments in registers: lane holds row (row0+L), k-slice g*8 of each ks
    bf16x8 a[16];
    const u16* arow = zq + (row0 + L) * EMB + g * 8;
#pragma unroll
    for (int ks = 0; ks < 16; ++ks) a[ks] = *(const bf16x8*)(arow + ks * 32);

    float q2v[4];
#pragma unroll
    for (int j = 0; j < 4; ++j) q2v[j] = q2[row0 + g * 4 + j];
    float p2v[16];
#pragma unroll
    for (int i = 0; i < 16; ++i) p2v[i] = p2[i * 16 + L];

    f32x4 acc[16];
#pragma unroll
    for (int i = 0; i < 16; ++i) acc[i] = f32x4{0.f, 0.f, 0.f, 0.f};

    for (int c = 0; c < 8; ++c) {
        if (c) __syncthreads();            // prior chunk's LDS reads complete
        // stage 32 ways x 512 cols: 2048 granules of 16B over 256 threads
#pragma unroll
        for (int p = 0; p < 8; ++p) {
            int gi = t + p * 256;
            int kc = gi >> 7, way = (gi >> 2) & 31, slot = gi & 3;
            int s = slot ^ ((way >> 1) & 3);   // pre-swizzled source (dest stays linear)
            gl_lds16(zp + (size_t)(c * 32 + way) * EMB + kc * 32 + s * 8,
                     ((u16*)zps) + gi * 8);
        }
        asm volatile("s_waitcnt vmcnt(0)" ::: "memory");
        __syncthreads();                   // chunk landed
#pragma unroll
        for (int ks = 0; ks < 16; ++ks) {
#pragma unroll
            for (int nt = 0; nt < 2; ++nt) {
                bf16x8 b = *(const bf16x8*)&zps[ks][swz16(nt * 16 + L, g)];
                acc[c * 2 + nt] = __builtin_amdgcn_mfma_f32_16x16x32_bf16(a[ks], b, acc[c * 2 + nt], 0, 0, 0);
            }
        }
    }

    // distances + wave-local softmax (C layout: row = g*4+j, col/way = i*16+L)
    float mx[4] = {-1e30f, -1e30f, -1e30f, -1e30f};
#pragma unroll
    for (int i = 0; i < 16; ++i)
#pragma unroll
        for (int j = 0; j < 4; ++j) {
            float d2 = q2v[j] + p2v[i] - 2.f * acc[i][j];
            float s = -sqrtf(fmaxf(d2, 0.f));
            acc[i][j] = s;
            mx[j] = fmaxf(mx[j], s);
        }
#pragma unroll
    for (int j = 0; j < 4; ++j)
#pragma unroll
        for (int m = 1; m < 16; m <<= 1) mx[j] = fmaxf(mx[j], __shfl_xor(mx[j], m));

    float sm[4] = {0.f, 0.f, 0.f, 0.f};
#pragma unroll
    for (int i = 0; i < 16; ++i)
#pragma unroll
        for (int j = 0; j < 4; ++j) {
            float e = __expf(acc[i][j] - mx[j]);
            acc[i][j] = e;
            sm[j] += e;
        }
#pragma unroll
    for (int j = 0; j < 4; ++j) {
#pragma unroll
        for (int m = 1; m < 16; m <<= 1) sm[j] += __shfl_xor(sm[j], m);
        sm[j] = 1.f / sm[j];
    }
#pragma unroll
    for (int i = 0; i < 16; ++i)
#pragma unroll
        for (int j = 0; j < 4; ++j)
            out[(row0 + g * 4 + j) * WAYS + i * 16 + L] = acc[i][j] * sm[j];
}

// ---------------- launch ----------------
extern "C" void kernel_launch(void* const* d_in, const int* in_sizes, int n_in,
                              void* d_out, int out_size, void* d_ws, size_t ws_size,
                              hipStream_t stream) {
    (void)in_sizes; (void)n_in; (void)out_size; (void)ws_size;
    const float* simg = (const float*)d_in[0];
    const int*   slab = (const int*)d_in[1];
    const float* qimg = (const float*)d_in[2];
    const float* W    = (const float*)d_in[3];
    // d_in[4] = b : omitted on purpose (cancels in euclidean distance)
    float* out = (float*)d_out;
    char* ws = (char*)d_ws;

    int*   labels = (int*)  (ws + 0);          // 256 KiB
    int*   perm   = (int*)  (ws + 262144);     // 256 KiB
    int*   icounts= (int*)  (ws + 524288);     // 1 KiB
    int*   offs   = (int*)  (ws + 525312);     // 1 KiB
    int*   cursor = (int*)  (ws + 526336);     // 1 KiB
    float* countsF= (float*)(ws + 527360);     // 1 KiB
    float* sums   = (float*)(ws + 528384);     // 1 MiB
    float* p2     = (float*)(ws + 1576960);    // 1 KiB
    u16*   zpb    = (u16*)  (ws + 1577984);    // 256 KiB
    u16*   Wt     = (u16*)  (ws + 1840128);    // 1 MiB
    u16*   zq     = (u16*)  (ws + 2888704);    // 64 MiB
    float* q2     = (float*)(ws + 69997568);   // 256 KiB (final, summed in k13)

    // NO hipMemsetAsync: icounts zeroed in k0; zq/q2/sums fully overwritten before reads.

    k0_transpose <<<128,        256, 0, stream>>>(W, Wt, icounts);
    k1a_labels   <<<NSUP / 4,   256, 0, stream>>>(slab, labels, icounts);
    k1p_prefix   <<<1,          256, 0, stream>>>(icounts, offs, cursor, countsF);
    k1s_scatter  <<<NSUP / 256, 256, 0, stream>>>(labels, cursor, perm);
    k13_fused    <<<768,        1024, 0, stream>>>(qimg, Wt, zq, q2,
                                                   simg, perm, offs, icounts, sums);
    k2_proto     <<<WAYS,       512, 0, stream>>>(sums, countsF, W, zpb, p2);
    k4_scores    <<<NQRY / 64,  256, 0, stream>>>(zq, zpb, q2, p2, out);
}